// Round 6
// baseline (264.192 us; speedup 1.0000x reference)
//
#include <hip/hip_runtime.h>
#include <hip/hip_bf16.h>
#include <math.h>

// Reassociated TemplateColumnWiseAttention (single query row):
//   k_cvtW : weight transposes/converts (wqT,wgT,wvT,woT,wkbf) bf16
//   k_qg   : q = (s@wq)*0.125 -> Qbf ; g = sigmoid(s@wg+bg) -> Gbf   (MFMA)
//   k_r    : r[n,h,c] = sum_ch q[n,h,ch] wk[c,h*64+ch] -> Rbf        (MFMA)
//   k_main : per (b, 8-n tile), 2 blocks/CU:
//              scores = X r + bias (MFMA, wave0) ; softmax in-reg
//              y = a^T X (VALU, wave=head) -> Yl
//              o = y @ wvT (MFMA, M=16/8-valid), gate from regs
//              out = (o*g) @ woT + bo (MFMA, direct store)

namespace {

constexpr int BN = 4096;  // B*N rows

typedef __bf16 bf16x8 __attribute__((ext_vector_type(8)));
typedef __bf16 bf16x4 __attribute__((ext_vector_type(4)));
typedef float vf4 __attribute__((ext_vector_type(4)));

__device__ __forceinline__ __bf16 f2b(float f) { return (__bf16)f; }

// ---------------- weight conversion / transpose ----------------
template <int SK, int SN>
__device__ __forceinline__ void transpose_tile(const float* __restrict__ src,
                                               __bf16* __restrict__ dst,
                                               float (*T)[33], int tloc,
                                               int tid) {
  constexpr int ntn = SN / 32;
  const int tkb = tloc / ntn, tnb = tloc % ntn;
  const int row = tid >> 3, c4 = tid & 7;
  float4 v = *(const float4*)&src[(size_t)(tkb * 32 + row) * SN + tnb * 32 + c4 * 4];
  T[row][c4 * 4 + 0] = v.x;
  T[row][c4 * 4 + 1] = v.y;
  T[row][c4 * 4 + 2] = v.z;
  T[row][c4 * 4 + 3] = v.w;
  __syncthreads();
  const int nr = tid >> 3, k4 = tid & 7;
  bf16x4 o;
#pragma unroll
  for (int q = 0; q < 4; ++q) o[q] = f2b(T[k4 * 4 + q][nr]);
  *(bf16x4*)&dst[(size_t)(tnb * 32 + nr) * SK + tkb * 32 + k4 * 4] = o;
}

__global__ __launch_bounds__(256) void k_cvtW(
    const float* __restrict__ wq, const float* __restrict__ wg,
    const float* __restrict__ wk, const float* __restrict__ wv,
    const float* __restrict__ wo, __bf16* __restrict__ wqT,
    __bf16* __restrict__ wgT, __bf16* __restrict__ wkbf,
    __bf16* __restrict__ wvT, __bf16* __restrict__ woT) {
  __shared__ float T[32][33];
  const int bid = blockIdx.x, tid = threadIdx.x;
  if (bid < 128) {  // wk convert (no transpose)
    size_t i = (size_t)bid * 1024 + tid * 4;
    float4 v = *(const float4*)&wk[i];
    bf16x4 o = {f2b(v.x), f2b(v.y), f2b(v.z), f2b(v.w)};
    *(bf16x4*)&wkbf[i] = o;
  } else if (bid < 256) {
    transpose_tile<256, 512>(wq, wqT, T, bid - 128, tid);
  } else if (bid < 384) {
    transpose_tile<256, 512>(wg, wgT, T, bid - 256, tid);
  } else if (bid < 512) {
    transpose_tile<256, 512>(wv, wvT, T, bid - 384, tid);
  } else {
    transpose_tile<512, 256>(wo, woT, T, bid - 512, tid);
  }
}

// ---------------- MFMA tile core (64x64 tile, 4 waves 2x2, BK=32) ----------
__device__ __forceinline__ void mfma_tile(const __bf16 (*Al)[40],
                                          const __bf16 (*Bl)[40], int lane,
                                          int wm, int wn, vf4 acc[2][2]) {
  const int kg = lane >> 4, lr = lane & 15;
  bf16x8 a0 = *(const bf16x8*)&Al[wm * 32 + lr][kg * 8];
  bf16x8 a1 = *(const bf16x8*)&Al[wm * 32 + 16 + lr][kg * 8];
  bf16x8 b0 = *(const bf16x8*)&Bl[wn * 32 + lr][kg * 8];
  bf16x8 b1 = *(const bf16x8*)&Bl[wn * 32 + 16 + lr][kg * 8];
  acc[0][0] = __builtin_amdgcn_mfma_f32_16x16x32_bf16(a0, b0, acc[0][0], 0, 0, 0);
  acc[0][1] = __builtin_amdgcn_mfma_f32_16x16x32_bf16(a0, b1, acc[0][1], 0, 0, 0);
  acc[1][0] = __builtin_amdgcn_mfma_f32_16x16x32_bf16(a1, b0, acc[1][0], 0, 0, 0);
  acc[1][1] = __builtin_amdgcn_mfma_f32_16x16x32_bf16(a1, b1, acc[1][1], 0, 0, 0);
}

// ---------------- k_qg: Qbf = (s@wq)*.125 ; Gbf = sigmoid(s@wg+bg) ---------
// K-loop with register prefetch of step k+1 issued before MFMA of step k.
__global__ __launch_bounds__(256) void k_qg(const float* __restrict__ s,
                                            const __bf16* __restrict__ wqT,
                                            const __bf16* __restrict__ wgT,
                                            const float* __restrict__ bg,
                                            __bf16* __restrict__ Qbf,
                                            __bf16* __restrict__ Gbf) {
  __shared__ __bf16 Al[64][40], Bl[64][40];
  const int tid = threadIdx.x, lane = tid & 63, w = tid >> 6;
  const int wm = w >> 1, wn = w & 1;
  const int rb = blockIdx.x * 64, by = blockIdx.y;
  const __bf16* Bsrc =
      (by < 8) ? wqT + (size_t)(by * 64) * 256 : wgT + (size_t)((by - 8) * 64) * 256;
  vf4 acc[2][2] = {};
  const int srow = tid >> 2, skg = tid & 3;
  const float* sA = &s[(size_t)(rb + srow) * 256 + skg * 8];
  const __bf16* sB = &Bsrc[(size_t)srow * 256 + skg * 8];
  float4 a1 = *(const float4*)(sA);
  float4 a2 = *(const float4*)(sA + 4);
  bf16x8 bv = *(const bf16x8*)(sB);
  for (int k0 = 0; k0 < 256; k0 += 32) {
    bf16x8 av = {f2b(a1.x), f2b(a1.y), f2b(a1.z), f2b(a1.w),
                 f2b(a2.x), f2b(a2.y), f2b(a2.z), f2b(a2.w)};
    *(bf16x8*)&Al[srow][skg * 8] = av;
    *(bf16x8*)&Bl[srow][skg * 8] = bv;
    if (k0 < 224) {  // prefetch next step; overlaps barrier + MFMA
      a1 = *(const float4*)(sA + k0 + 32);
      a2 = *(const float4*)(sA + k0 + 36);
      bv = *(const bf16x8*)(sB + k0 + 32);
    }
    __syncthreads();
    mfma_tile(Al, Bl, lane, wm, wn, acc);
    __syncthreads();
  }
  const int r4 = (lane >> 4) * 4, cl = lane & 15;
#pragma unroll
  for (int mi = 0; mi < 2; ++mi)
#pragma unroll
    for (int ni = 0; ni < 2; ++ni) {
      vf4 v = acc[mi][ni];
#pragma unroll
      for (int j = 0; j < 4; ++j) {
        int row = rb + wm * 32 + mi * 16 + r4 + j;
        int col = by * 64 + wn * 32 + ni * 16 + cl;
        if (by < 8) {
          Qbf[(size_t)row * 512 + col] = f2b(v[j] * 0.125f);
        } else {
          int c = col - 512;
          Gbf[(size_t)row * 512 + c] =
              f2b(1.f / (1.f + __expf(-(v[j] + bg[c]))));
        }
      }
    }
}

// ---------------- k_r: Rbf[n, h*256+c] = q[n,h,:]·wk[c, h*64+:] ------------
__global__ __launch_bounds__(256) void k_r(const __bf16* __restrict__ Qbf,
                                           const __bf16* __restrict__ wkbf,
                                           __bf16* __restrict__ Rbf) {
  __shared__ __bf16 Al[64][40], Bl[64][40];
  const int tid = threadIdx.x, lane = tid & 63, w = tid >> 6;
  const int wm = w >> 1, wn = w & 1;
  const int rb = blockIdx.x * 64, by = blockIdx.y;
  const int h = by >> 2, ct = by & 3;
  vf4 acc[2][2] = {};
  const int srow = tid >> 2, skg = tid & 3;
  const __bf16* qA = &Qbf[(size_t)(rb + srow) * 512 + h * 64 + skg * 8];
  const __bf16* wB = &wkbf[(size_t)(ct * 64 + srow) * 512 + h * 64 + skg * 8];
  bf16x8 av = *(const bf16x8*)(qA);
  bf16x8 bv = *(const bf16x8*)(wB);
  for (int k0 = 0; k0 < 64; k0 += 32) {
    *(bf16x8*)&Al[srow][skg * 8] = av;
    *(bf16x8*)&Bl[srow][skg * 8] = bv;
    if (k0 == 0) {
      av = *(const bf16x8*)(qA + 32);
      bv = *(const bf16x8*)(wB + 32);
    }
    __syncthreads();
    mfma_tile(Al, Bl, lane, wm, wn, acc);
    __syncthreads();
  }
  const int r4 = (lane >> 4) * 4, cl = lane & 15;
#pragma unroll
  for (int mi = 0; mi < 2; ++mi)
#pragma unroll
    for (int ni = 0; ni < 2; ++ni) {
      vf4 v = acc[mi][ni];
#pragma unroll
      for (int j = 0; j < 4; ++j) {
        int row = rb + wm * 32 + mi * 16 + r4 + j;
        int col = h * 256 + ct * 64 + wn * 32 + ni * 16 + cl;
        Rbf[(size_t)row * 2048 + col] = f2b(v[j]);
      }
    }
}

// ---------------- k_main: fused attn + o + gate + out ----------------------
// grid = 512 blocks (b x 128 n-tiles of 8), 512 threads, 2 blocks/CU.
// LDS 75.5 KB: Xb(2x32x264) aliased later by oS(16x552); Yl 8x8x264;
// rb 2x8x264; aS/bias.
__global__ __launch_bounds__(512, 4) void k_main(
    const float* __restrict__ tin, const float* __restrict__ mask,
    const __bf16* __restrict__ Rbf, const __bf16* __restrict__ Gbf,
    const __bf16* __restrict__ wvT, const __bf16* __restrict__ woT,
    const float* __restrict__ bo, float* __restrict__ out) {
  __shared__ __align__(16) char uni[2 * 32 * 264 * 2];  // Xb, later oS
  __shared__ __bf16 Yl[8][8][264];
  __shared__ __bf16 rbuf[2][8][264];
  __shared__ float aS[8][36];
  __shared__ float biasS[32];
  typedef __bf16 (*XbT)[32][264];
  typedef __bf16 (*OsT)[552];
  XbT Xb = (XbT)uni;
  OsT oS = (OsT)uni;

  const int tid = threadIdx.x, lane = tid & 63, wid = tid >> 6;
  const int b = blockIdx.x >> 7;
  const int n0 = (blockIdx.x & 127) * 8;
  const int bn0 = b * 1024 + n0;

  // gate held in registers: thread tid owns g[n=tid>>6][(tid&63)*8 .. +7]
  const bf16x8 gv =
      *(const bf16x8*)&Gbf[(size_t)(bn0 + (tid >> 6)) * 512 + (tid & 63) * 8];

  // ---- phase 0: bias, r(0), X(0) ----
  if (tid < 32) biasS[tid] = 1e9f * (mask[b * 32 + tid] - 1.0f);
  if (tid < 256)
    *(bf16x8*)&rbuf[0][tid >> 5][(tid & 31) * 8] =
        *(const bf16x8*)&Rbf[(size_t)bn0 * 2048 + tid * 8];
  {
    const size_t base = (size_t)b * 8388608 + (size_t)n0 * 256;
#pragma unroll
    for (int p = 0; p < 4; ++p) {
      int i = p * 512 + tid;
      int tt = i >> 6, c4 = i & 63;
      float4 v = *(const float4*)&tin[base + (size_t)tt * 262144 + c4 * 4];
      bf16x4 o4 = {f2b(v.x), f2b(v.y), f2b(v.z), f2b(v.w)};
      *(bf16x4*)&Xb[0][tt][c4 * 4] = o4;
    }
  }
  __syncthreads();

  // ---- phase 1: per-n {prefetch X/r, scores(w0), softmax, PV(all)} ----
  for (int n = 0; n < 8; ++n) {
    const int cur = n & 1;
    float4 xr[4];
    bf16x8 rv;
    if (n < 7) {  // issue next-n loads; consumed after PV
      const size_t base = (size_t)b * 8388608 + (size_t)(n0 + n + 1) * 256;
#pragma unroll
      for (int p = 0; p < 4; ++p) {
        int i = p * 512 + tid;
        xr[p] = *(const float4*)&tin[base + (size_t)(i >> 6) * 262144 + (i & 63) * 4];
      }
      if (tid < 256)
        rv = *(const bf16x8*)&Rbf[(size_t)(bn0 + n + 1) * 2048 + tid * 8];
    }
    if (wid == 0) {  // scores: M=32(t) x N=16(8h dup) x K=256
      vf4 d0 = {0.f, 0.f, 0.f, 0.f}, d1 = {0.f, 0.f, 0.f, 0.f};
      const int hh = lane & 7, kg = lane >> 4;
#pragma unroll
      for (int k8 = 0; k8 < 8; ++k8) {
        bf16x8 bfr = *(const bf16x8*)&rbuf[cur][hh][k8 * 32 + kg * 8];
        bf16x8 a0 = *(const bf16x8*)&Xb[cur][lane & 15][k8 * 32 + kg * 8];
        bf16x8 a1 = *(const bf16x8*)&Xb[cur][16 + (lane & 15)][k8 * 32 + kg * 8];
        d0 = __builtin_amdgcn_mfma_f32_16x16x32_bf16(a0, bfr, d0, 0, 0, 0);
        d1 = __builtin_amdgcn_mfma_f32_16x16x32_bf16(a1, bfr, d1, 0, 0, 0);
      }
      float sc[8];
#pragma unroll
      for (int j = 0; j < 4; ++j) {
        int t = (lane >> 4) * 4 + j;
        sc[j] = d0[j] + biasS[t];
        sc[4 + j] = d1[j] + biasS[16 + t];
      }
      float m = sc[0];
#pragma unroll
      for (int j = 1; j < 8; ++j) m = fmaxf(m, sc[j]);
      m = fmaxf(m, __shfl_xor(m, 16));
      m = fmaxf(m, __shfl_xor(m, 32));
      float e[8], sum = 0.f;
#pragma unroll
      for (int j = 0; j < 8; ++j) {
        e[j] = __expf(sc[j] - m);
        sum += e[j];
      }
      sum += __shfl_xor(sum, 16);
      sum += __shfl_xor(sum, 32);
      const float rs = 1.f / sum;
      if ((lane & 15) < 8) {
        const int h = lane & 15;
#pragma unroll
        for (int j = 0; j < 4; ++j) {
          aS[h][(lane >> 4) * 4 + j] = e[j] * rs;
          aS[h][16 + (lane >> 4) * 4 + j] = e[4 + j] * rs;
        }
      }
    }
    __syncthreads();  // aS ready

    {  // PV: wave = head; y -> Yl[n][h]
      float acc0 = 0.f, acc1 = 0.f, acc2 = 0.f, acc3 = 0.f;
#pragma unroll
      for (int tt = 0; tt < 32; ++tt) {
        const float a = aS[wid][tt];
        bf16x4 xv = *(const bf16x4*)&Xb[cur][tt][lane * 4];
        acc0 = fmaf(a, (float)xv[0], acc0);
        acc1 = fmaf(a, (float)xv[1], acc1);
        acc2 = fmaf(a, (float)xv[2], acc2);
        acc3 = fmaf(a, (float)xv[3], acc3);
      }
      bf16x4 y4 = {f2b(acc0), f2b(acc1), f2b(acc2), f2b(acc3)};
      *(bf16x4*)&Yl[n][wid][lane * 4] = y4;
    }
    if (n < 7) {  // commit prefetches
#pragma unroll
      for (int p = 0; p < 4; ++p) {
        int i = p * 512 + tid;
        bf16x4 o4 = {f2b(xr[p].x), f2b(xr[p].y), f2b(xr[p].z), f2b(xr[p].w)};
        *(bf16x4*)&Xb[cur ^ 1][i >> 6][(i & 63) * 4] = o4;
      }
      if (tid < 256)
        *(bf16x8*)&rbuf[cur ^ 1][tid >> 5][(tid & 31) * 8] = rv;
    }
    __syncthreads();
  }
  // Xb dead from here; oS aliases it.

  // ---- phase 2: o = y @ wvT per head (wave = head), M=16 (rows 0-7 valid) --
  {
    const int lr = lane & 15, kg = lane >> 4;
    vf4 acc[4] = {};
#pragma unroll
    for (int k8 = 0; k8 < 8; ++k8) {
      bf16x8 afr = *(const bf16x8*)&Yl[lr & 7][wid][k8 * 32 + kg * 8];
#pragma unroll
      for (int ct = 0; ct < 4; ++ct) {
        bf16x8 bfr = *(const bf16x8*)&wvT[(size_t)(wid * 64 + ct * 16 + lr) * 256 +
                                          k8 * 32 + kg * 8];
        acc[ct] = __builtin_amdgcn_mfma_f32_16x16x32_bf16(afr, bfr, acc[ct], 0, 0, 0);
      }
    }
#pragma unroll
    for (int ct = 0; ct < 4; ++ct)
#pragma unroll
      for (int j = 0; j < 4; ++j) {
        int row = kg * 4 + j;
        int col = wid * 64 + ct * 16 + lr;
        oS[row][col] = f2b(acc[ct][j]);
      }
  }
  __syncthreads();

  // ---- gate pass: oS[row][c] *= g (registers), rows 0-7 ----
  {
    const int row = tid >> 6, c8 = (tid & 63) * 8;
    bf16x8 ov = *(const bf16x8*)&oS[row][c8];
#pragma unroll
    for (int j = 0; j < 8; ++j) ov[j] = f2b((float)ov[j] * (float)gv[j]);
    *(bf16x8*)&oS[row][c8] = ov;
  }
  __syncthreads();

  // ---- phase 3: out = oS @ woT + bo (wave w: col tiles 2w, 2w+1) ----
  {
    const int lr = lane & 15, kg = lane >> 4;
    vf4 acc[2] = {};
#pragma unroll
    for (int k8 = 0; k8 < 16; ++k8) {
      bf16x8 afr = *(const bf16x8*)&oS[lr][k8 * 32 + kg * 8];
#pragma unroll
      for (int cc = 0; cc < 2; ++cc) {
        int cb = (wid * 2 + cc) * 16;
        bf16x8 bfr =
            *(const bf16x8*)&woT[(size_t)(cb + lr) * 512 + k8 * 32 + kg * 8];
        acc[cc] = __builtin_amdgcn_mfma_f32_16x16x32_bf16(afr, bfr, acc[cc], 0, 0, 0);
      }
    }
#pragma unroll
    for (int cc = 0; cc < 2; ++cc) {
      const int col = (wid * 2 + cc) * 16 + lr;
      const float bov = bo[col];
#pragma unroll
      for (int j = 0; j < 4; ++j) {
        int row = kg * 4 + j;
        if (row < 8)
          out[(size_t)(bn0 + row) * 256 + col] = acc[cc][j] + bov;
      }
    }
  }
}

}  // namespace

extern "C" void kernel_launch(void* const* d_in, const int* in_sizes, int n_in,
                              void* d_out, int out_size, void* d_ws,
                              size_t ws_size, hipStream_t stream) {
  const float* t = (const float*)d_in[0];
  const float* s = (const float*)d_in[1];
  const float* msk = (const float*)d_in[2];
  const float* wq = (const float*)d_in[3];
  const float* wk = (const float*)d_in[4];
  const float* wv = (const float*)d_in[5];
  const float* wg = (const float*)d_in[6];
  const float* bg = (const float*)d_in[7];
  const float* wo = (const float*)d_in[8];
  const float* bo = (const float*)d_in[9];
  float* out = (float*)d_out;

  char* p = (char*)d_ws;
  __bf16* Qbf = (__bf16*)p;   p += (size_t)BN * 512 * 2;   // 4 MB
  __bf16* Gbf = (__bf16*)p;   p += (size_t)BN * 512 * 2;   // 4 MB
  __bf16* Rbf = (__bf16*)p;   p += (size_t)BN * 2048 * 2;  // 16 MB
  __bf16* wqT = (__bf16*)p;   p += 512 * 256 * 2;
  __bf16* wgT = (__bf16*)p;   p += 512 * 256 * 2;
  __bf16* wvT = (__bf16*)p;   p += 512 * 256 * 2;
  __bf16* woT = (__bf16*)p;   p += 256 * 512 * 2;
  __bf16* wkbf = (__bf16*)p;  p += 256 * 512 * 2;

  k_cvtW<<<640, 256, 0, stream>>>(wq, wg, wk, wv, wo, wqT, wgT, wkbf, wvT, woT);
  k_qg<<<dim3(BN / 64, 16), 256, 0, stream>>>(s, wqT, wgT, bg, Qbf, Gbf);
  k_r<<<dim3(BN / 64, 32), 256, 0, stream>>>(Qbf, wkbf, Rbf);
  k_main<<<512, 512, 0, stream>>>(t, msk, Rbf, Gbf, wvT, woT, bo, out);
}

// Round 7
// 246.978 us; speedup vs baseline: 1.0697x; 1.0697x over previous
//
#include <hip/hip_runtime.h>
#include <hip/hip_bf16.h>
#include <math.h>

// Reassociated TemplateColumnWiseAttention (single query row):
//   k_cvtW : weight transposes/converts (wqT,wgT,wkbf,wvT,woT) bf16
//   k_qg   : q = (s@wq)*0.125 -> Qbf ; g = sigmoid(s@wg+bg) -> Gbf   (MFMA)
//   k_r    : r[n,h,c] = sum_ch q[n,h,ch] wk[c,h*64+ch] -> Rbf        (MFMA)
//   k_attn : per (b,n) block (4096 blocks, 256 thr): scores = X r + bias,
//            softmax, y = a^T X -> Ybf                               (VALU)
//   k_og   : og = (y @ wvT) * g -> OGbf                              (MFMA)
//   k_out  : out = og @ woT + bo                                     (MFMA)

namespace {

constexpr int Nn = 1024, Cc = 256;
constexpr int BN = 4096;  // B*N rows

typedef __bf16 bf16x8 __attribute__((ext_vector_type(8)));
typedef __bf16 bf16x4 __attribute__((ext_vector_type(4)));
typedef float vf4 __attribute__((ext_vector_type(4)));

__device__ __forceinline__ __bf16 f2b(float f) { return (__bf16)f; }

// ---------------- weight conversion / transpose ----------------
template <int SK, int SN>
__device__ __forceinline__ void transpose_tile(const float* __restrict__ src,
                                               __bf16* __restrict__ dst,
                                               float (*T)[33], int tloc,
                                               int tid) {
  constexpr int ntn = SN / 32;
  const int tkb = tloc / ntn, tnb = tloc % ntn;
  const int row = tid >> 3, c4 = tid & 7;
  float4 v = *(const float4*)&src[(size_t)(tkb * 32 + row) * SN + tnb * 32 + c4 * 4];
  T[row][c4 * 4 + 0] = v.x;
  T[row][c4 * 4 + 1] = v.y;
  T[row][c4 * 4 + 2] = v.z;
  T[row][c4 * 4 + 3] = v.w;
  __syncthreads();
  const int nr = tid >> 3, k4 = tid & 7;
  bf16x4 o;
#pragma unroll
  for (int q = 0; q < 4; ++q) o[q] = f2b(T[k4 * 4 + q][nr]);
  *(bf16x4*)&dst[(size_t)(tnb * 32 + nr) * SK + tkb * 32 + k4 * 4] = o;
}

__global__ __launch_bounds__(256) void k_cvtW(
    const float* __restrict__ wq, const float* __restrict__ wg,
    const float* __restrict__ wk, const float* __restrict__ wv,
    const float* __restrict__ wo, __bf16* __restrict__ wqT,
    __bf16* __restrict__ wgT, __bf16* __restrict__ wkbf,
    __bf16* __restrict__ wvT, __bf16* __restrict__ woT) {
  __shared__ float T[32][33];
  const int bid = blockIdx.x, tid = threadIdx.x;
  if (bid < 128) {  // wk convert (no transpose)
    size_t i = (size_t)bid * 1024 + tid * 4;
    float4 v = *(const float4*)&wk[i];
    bf16x4 o = {f2b(v.x), f2b(v.y), f2b(v.z), f2b(v.w)};
    *(bf16x4*)&wkbf[i] = o;
  } else if (bid < 256) {
    transpose_tile<256, 512>(wq, wqT, T, bid - 128, tid);
  } else if (bid < 384) {
    transpose_tile<256, 512>(wg, wgT, T, bid - 256, tid);
  } else if (bid < 512) {
    transpose_tile<256, 512>(wv, wvT, T, bid - 384, tid);
  } else {
    transpose_tile<512, 256>(wo, woT, T, bid - 512, tid);
  }
}

// ---------------- MFMA tile core (64x64 tile, 4 waves 2x2, BK=32) ----------
__device__ __forceinline__ void mfma_tile(const __bf16 (*Al)[40],
                                          const __bf16 (*Bl)[40], int lane,
                                          int wm, int wn, vf4 acc[2][2]) {
  const int kg = lane >> 4, lr = lane & 15;
  bf16x8 a0 = *(const bf16x8*)&Al[wm * 32 + lr][kg * 8];
  bf16x8 a1 = *(const bf16x8*)&Al[wm * 32 + 16 + lr][kg * 8];
  bf16x8 b0 = *(const bf16x8*)&Bl[wn * 32 + lr][kg * 8];
  bf16x8 b1 = *(const bf16x8*)&Bl[wn * 32 + 16 + lr][kg * 8];
  acc[0][0] = __builtin_amdgcn_mfma_f32_16x16x32_bf16(a0, b0, acc[0][0], 0, 0, 0);
  acc[0][1] = __builtin_amdgcn_mfma_f32_16x16x32_bf16(a0, b1, acc[0][1], 0, 0, 0);
  acc[1][0] = __builtin_amdgcn_mfma_f32_16x16x32_bf16(a1, b0, acc[1][0], 0, 0, 0);
  acc[1][1] = __builtin_amdgcn_mfma_f32_16x16x32_bf16(a1, b1, acc[1][1], 0, 0, 0);
}

// ---------------- k_qg: Qbf = (s@wq)*.125 ; Gbf = sigmoid(s@wg+bg) ---------
__global__ __launch_bounds__(256) void k_qg(const float* __restrict__ s,
                                            const __bf16* __restrict__ wqT,
                                            const __bf16* __restrict__ wgT,
                                            const float* __restrict__ bg,
                                            __bf16* __restrict__ Qbf,
                                            __bf16* __restrict__ Gbf) {
  __shared__ __bf16 Al[64][40], Bl[64][40];
  const int tid = threadIdx.x, lane = tid & 63, w = tid >> 6;
  const int wm = w >> 1, wn = w & 1;
  const int rb = blockIdx.x * 64, by = blockIdx.y;
  const __bf16* Bsrc =
      (by < 8) ? wqT + (size_t)(by * 64) * 256 : wgT + (size_t)((by - 8) * 64) * 256;
  vf4 acc[2][2] = {};
  const int srow = tid >> 2, skg = tid & 3;
  const float* sA = &s[(size_t)(rb + srow) * 256 + skg * 8];
  const __bf16* sB = &Bsrc[(size_t)srow * 256 + skg * 8];
  float4 a1 = *(const float4*)(sA);
  float4 a2 = *(const float4*)(sA + 4);
  bf16x8 bv = *(const bf16x8*)(sB);
  for (int k0 = 0; k0 < 256; k0 += 32) {
    bf16x8 av = {f2b(a1.x), f2b(a1.y), f2b(a1.z), f2b(a1.w),
                 f2b(a2.x), f2b(a2.y), f2b(a2.z), f2b(a2.w)};
    *(bf16x8*)&Al[srow][skg * 8] = av;
    *(bf16x8*)&Bl[srow][skg * 8] = bv;
    if (k0 < 224) {  // prefetch next step; overlaps barrier + MFMA
      a1 = *(const float4*)(sA + k0 + 32);
      a2 = *(const float4*)(sA + k0 + 36);
      bv = *(const bf16x8*)(sB + k0 + 32);
    }
    __syncthreads();
    mfma_tile(Al, Bl, lane, wm, wn, acc);
    __syncthreads();
  }
  const int r4 = (lane >> 4) * 4, cl = lane & 15;
#pragma unroll
  for (int mi = 0; mi < 2; ++mi)
#pragma unroll
    for (int ni = 0; ni < 2; ++ni) {
      vf4 v = acc[mi][ni];
#pragma unroll
      for (int j = 0; j < 4; ++j) {
        int row = rb + wm * 32 + mi * 16 + r4 + j;
        int col = by * 64 + wn * 32 + ni * 16 + cl;
        if (by < 8) {
          Qbf[(size_t)row * 512 + col] = f2b(v[j] * 0.125f);
        } else {
          int c = col - 512;
          Gbf[(size_t)row * 512 + c] =
              f2b(1.f / (1.f + __expf(-(v[j] + bg[c]))));
        }
      }
    }
}

// ---------------- k_r: Rbf[n, h*256+c] = q[n,h,:]·wk[c, h*64+:] ------------
__global__ __launch_bounds__(256) void k_r(const __bf16* __restrict__ Qbf,
                                           const __bf16* __restrict__ wkbf,
                                           __bf16* __restrict__ Rbf) {
  __shared__ __bf16 Al[64][40], Bl[64][40];
  const int tid = threadIdx.x, lane = tid & 63, w = tid >> 6;
  const int wm = w >> 1, wn = w & 1;
  const int rb = blockIdx.x * 64, by = blockIdx.y;
  const int h = by >> 2, ct = by & 3;
  vf4 acc[2][2] = {};
  const int srow = tid >> 2, skg = tid & 3;
  const __bf16* qA = &Qbf[(size_t)(rb + srow) * 512 + h * 64 + skg * 8];
  const __bf16* wB = &wkbf[(size_t)(ct * 64 + srow) * 512 + h * 64 + skg * 8];
  bf16x8 av = *(const bf16x8*)(qA);
  bf16x8 bv = *(const bf16x8*)(wB);
  for (int k0 = 0; k0 < 64; k0 += 32) {
    *(bf16x8*)&Al[srow][skg * 8] = av;
    *(bf16x8*)&Bl[srow][skg * 8] = bv;
    if (k0 == 0) {
      av = *(const bf16x8*)(qA + 32);
      bv = *(const bf16x8*)(wB + 32);
    }
    __syncthreads();
    mfma_tile(Al, Bl, lane, wm, wn, acc);
    __syncthreads();
  }
  const int r4 = (lane >> 4) * 4, cl = lane & 15;
#pragma unroll
  for (int mi = 0; mi < 2; ++mi)
#pragma unroll
    for (int ni = 0; ni < 2; ++ni) {
      vf4 v = acc[mi][ni];
#pragma unroll
      for (int j = 0; j < 4; ++j) {
        int row = rb + wm * 32 + mi * 16 + r4 + j;
        int col = h * 256 + ct * 64 + wn * 32 + ni * 16 + cl;
        Rbf[(size_t)row * 2048 + col] = f2b(v[j]);
      }
    }
}

// ---------------- k_attn: per (b,n) scores/softmax/y -----------------------
// 4096 blocks x 256 threads, ~26.4 KB LDS -> 6 blocks/CU, 24 waves/CU.
__global__ __launch_bounds__(256) void k_attn(const float* __restrict__ tin,
                                              const float* __restrict__ mask,
                                              const __bf16* __restrict__ Rbf,
                                              __bf16* __restrict__ Y) {
  __shared__ __bf16 Xb[32][264];
  __shared__ float r_s[8][260];
  __shared__ float a_s[8][32];
  __shared__ float bias_s[32];
  const int ng = blockIdx.x;  // b*1024 + n
  const int b = ng >> 10, n = ng & (Nn - 1);
  const int tid = threadIdx.x;

  {  // stage r (bf16 -> fp32 LDS): thread tid handles chunk tid of 256
    bf16x8 rv = *(const bf16x8*)&Rbf[(size_t)ng * 2048 + tid * 8];
    const int h = tid >> 5, c8 = tid & 31;
    float4 f1 = {(float)rv[0], (float)rv[1], (float)rv[2], (float)rv[3]};
    float4 f2 = {(float)rv[4], (float)rv[5], (float)rv[6], (float)rv[7]};
    *(float4*)&r_s[h][c8 * 8] = f1;
    *(float4*)&r_s[h][c8 * 8 + 4] = f2;
  }
  const float* tb = tin + ((size_t)b * 32 * Nn + n) * Cc;
#pragma unroll
  for (int p = 0; p < 8; ++p) {
    int i = p * 256 + tid;  // float4 idx [0,2048)
    int tt = i >> 6, c4 = i & 63;
    float4 v = *(const float4*)&tb[(size_t)tt * Nn * Cc + c4 * 4];
    bf16x4 o = {f2b(v.x), f2b(v.y), f2b(v.z), f2b(v.w)};
    *(bf16x4*)&Xb[tt][c4 * 4] = o;
  }
  if (tid < 32) bias_s[tid] = 1e9f * (mask[b * 32 + tid] - 1.0f);
  __syncthreads();

  {  // scores + softmax; thread = (h = tid>>5, t = tid&31)
    const int tt = tid & 31, hh = tid >> 5;
    float av[8] = {};
#pragma unroll 4
    for (int kk = 0; kk < 32; ++kk) {
      bf16x8 xv = *(const bf16x8*)&Xb[tt][kk * 8];
      float4 r1 = *(const float4*)&r_s[hh][kk * 8];
      float4 r2 = *(const float4*)&r_s[hh][kk * 8 + 4];
      av[0] = fmaf((float)xv[0], r1.x, av[0]);
      av[1] = fmaf((float)xv[1], r1.y, av[1]);
      av[2] = fmaf((float)xv[2], r1.z, av[2]);
      av[3] = fmaf((float)xv[3], r1.w, av[3]);
      av[4] = fmaf((float)xv[4], r2.x, av[4]);
      av[5] = fmaf((float)xv[5], r2.y, av[5]);
      av[6] = fmaf((float)xv[6], r2.z, av[6]);
      av[7] = fmaf((float)xv[7], r2.w, av[7]);
    }
    float sc = ((av[0] + av[1]) + (av[2] + av[3])) +
               ((av[4] + av[5]) + (av[6] + av[7])) + bias_s[tt];
    float m = sc;
#pragma unroll
    for (int off = 16; off >= 1; off >>= 1) m = fmaxf(m, __shfl_xor(m, off));
    float e = __expf(sc - m);
    float sum = e;
#pragma unroll
    for (int off = 16; off >= 1; off >>= 1) sum += __shfl_xor(sum, off);
    a_s[hh][tt] = e / sum;
  }
  __syncthreads();

  {  // y[h, cc*8 .. +7] ; thread = (h = tid>>5, cc = tid&31)
    const int cc = tid & 31, hh = tid >> 5;
    float acc[8] = {};
#pragma unroll 8
    for (int tt = 0; tt < 32; ++tt) {
      const float a = a_s[hh][tt];
      bf16x8 xv = *(const bf16x8*)&Xb[tt][cc * 8];
#pragma unroll
      for (int j = 0; j < 8; ++j) acc[j] = fmaf(a, (float)xv[j], acc[j]);
    }
    bf16x8 o;
#pragma unroll
    for (int j = 0; j < 8; ++j) o[j] = f2b(acc[j]);
    *(bf16x8*)&Y[(size_t)ng * 2048 + hh * 256 + cc * 8] = o;
  }
}

// ---------------- k_og: og[n, h*64+c'] = (y[n,h,:]·wvT[h*64+c',:]) * g -----
__global__ __launch_bounds__(256) void k_og(const __bf16* __restrict__ Ybf,
                                            const __bf16* __restrict__ wvT,
                                            const __bf16* __restrict__ Gbf,
                                            __bf16* __restrict__ OGbf) {
  __shared__ __bf16 Al[64][40], Bl[64][40];
  const int tid = threadIdx.x, lane = tid & 63, w = tid >> 6;
  const int wm = w >> 1, wn = w & 1;
  const int rb = blockIdx.x * 64, h = blockIdx.y;
  vf4 acc[2][2] = {};
  const int srow = tid >> 2, skg = tid & 3;
  const __bf16* yA = &Ybf[(size_t)(rb + srow) * 2048 + h * 256 + skg * 8];
  const __bf16* wB = &wvT[(size_t)(h * 64 + srow) * 256 + skg * 8];
  bf16x8 av = *(const bf16x8*)(yA);
  bf16x8 bv = *(const bf16x8*)(wB);
  for (int k0 = 0; k0 < 256; k0 += 32) {
    *(bf16x8*)&Al[srow][skg * 8] = av;
    *(bf16x8*)&Bl[srow][skg * 8] = bv;
    if (k0 < 224) {
      av = *(const bf16x8*)(yA + k0 + 32);
      bv = *(const bf16x8*)(wB + k0 + 32);
    }
    __syncthreads();
    mfma_tile(Al, Bl, lane, wm, wn, acc);
    __syncthreads();
  }
  const int r4 = (lane >> 4) * 4, cl = lane & 15;
#pragma unroll
  for (int mi = 0; mi < 2; ++mi)
#pragma unroll
    for (int ni = 0; ni < 2; ++ni) {
      vf4 v = acc[mi][ni];
#pragma unroll
      for (int j = 0; j < 4; ++j) {
        int row = rb + wm * 32 + mi * 16 + r4 + j;
        int col = h * 64 + wn * 32 + ni * 16 + cl;
        float g = (float)Gbf[(size_t)row * 512 + col];
        OGbf[(size_t)row * 512 + col] = f2b(v[j] * g);
      }
    }
}

// ---------------- k_out: out = og @ woT + bo -------------------------------
__global__ __launch_bounds__(256) void k_out(const __bf16* __restrict__ OGbf,
                                             const __bf16* __restrict__ woT,
                                             const float* __restrict__ bo,
                                             float* __restrict__ out) {
  __shared__ __bf16 Al[64][40], Bl[64][40];
  const int tid = threadIdx.x, lane = tid & 63, w = tid >> 6;
  const int wm = w >> 1, wn = w & 1;
  const int rb = blockIdx.x * 64, by = blockIdx.y;
  vf4 acc[2][2] = {};
  const int srow = tid >> 2, skg = tid & 3;
  const __bf16* oA = &OGbf[(size_t)(rb + srow) * 512 + skg * 8];
  const __bf16* wB = &woT[(size_t)(by * 64 + srow) * 512 + skg * 8];
  bf16x8 av = *(const bf16x8*)(oA);
  bf16x8 bv = *(const bf16x8*)(wB);
  for (int k0 = 0; k0 < 512; k0 += 32) {  // K = 512
    *(bf16x8*)&Al[srow][skg * 8] = av;
    *(bf16x8*)&Bl[srow][skg * 8] = bv;
    if (k0 < 480) {
      av = *(const bf16x8*)(oA + k0 + 32);
      bv = *(const bf16x8*)(wB + k0 + 32);
    }
    __syncthreads();
    mfma_tile(Al, Bl, lane, wm, wn, acc);
    __syncthreads();
  }
  const int r4 = (lane >> 4) * 4, cl = lane & 15;
#pragma unroll
  for (int mi = 0; mi < 2; ++mi)
#pragma unroll
    for (int ni = 0; ni < 2; ++ni) {
      vf4 v = acc[mi][ni];
#pragma unroll
      for (int j = 0; j < 4; ++j) {
        int row = rb + wm * 32 + mi * 16 + r4 + j;
        int col = by * 64 + wn * 32 + ni * 16 + cl;
        out[(size_t)row * 256 + col] = v[j] + bo[col];
      }
    }
}

}  // namespace

extern "C" void kernel_launch(void* const* d_in, const int* in_sizes, int n_in,
                              void* d_out, int out_size, void* d_ws,
                              size_t ws_size, hipStream_t stream) {
  const float* t = (const float*)d_in[0];
  const float* s = (const float*)d_in[1];
  const float* msk = (const float*)d_in[2];
  const float* wq = (const float*)d_in[3];
  const float* wk = (const float*)d_in[4];
  const float* wv = (const float*)d_in[5];
  const float* wg = (const float*)d_in[6];
  const float* bg = (const float*)d_in[7];
  const float* wo = (const float*)d_in[8];
  const float* bo = (const float*)d_in[9];
  float* out = (float*)d_out;

  char* p = (char*)d_ws;
  __bf16* Qbf = (__bf16*)p;   p += (size_t)BN * 512 * 2;   // 4 MB
  __bf16* Gbf = (__bf16*)p;   p += (size_t)BN * 512 * 2;   // 4 MB
  __bf16* Rbf = (__bf16*)p;   p += (size_t)BN * 2048 * 2;  // 16 MB
  __bf16* Ybf = (__bf16*)p;   p += (size_t)BN * 2048 * 2;  // 16 MB
  __bf16* OGbf = (__bf16*)p;  p += (size_t)BN * 512 * 2;   // 4 MB
  __bf16* wqT = (__bf16*)p;   p += 512 * 256 * 2;
  __bf16* wgT = (__bf16*)p;   p += 512 * 256 * 2;
  __bf16* wvT = (__bf16*)p;   p += 512 * 256 * 2;
  __bf16* woT = (__bf16*)p;   p += 256 * 512 * 2;
  __bf16* wkbf = (__bf16*)p;  p += 256 * 512 * 2;

  k_cvtW<<<640, 256, 0, stream>>>(wq, wg, wk, wv, wo, wqT, wgT, wkbf, wvT, woT);
  k_qg<<<dim3(BN / 64, 16), 256, 0, stream>>>(s, wqT, wgT, bg, Qbf, Gbf);
  k_r<<<dim3(BN / 64, 32), 256, 0, stream>>>(Qbf, wkbf, Rbf);
  k_attn<<<dim3(BN), 256, 0, stream>>>(t, msk, Rbf, Ybf);
  k_og<<<dim3(BN / 64, 8), 256, 0, stream>>>(Ybf, wvT, Gbf, OGbf);
  k_out<<<dim3(BN / 64, 4), 256, 0, stream>>>(OGbf, woT, bo, out);
}